// Round 8
// baseline (224.204 us; speedup 1.0000x reference)
//
#include <hip/hip_runtime.h>
#include <hip/hip_cooperative_groups.h>
#include <hip/hip_bf16.h>
#include <math.h>

#define B_ 8192
#define P_ 24
#define Q_ 12
#define E_ 256
#define V_ 1000
#define TOK_ 36
#define NK_ 129      // knots
#define NI_ 128      // intervals
#define KT_ 8        // knots per build block
#define NKBLK_ 17    // ceil(129/8)
#define NBUILD_ (P_ * NKBLK_)           // 408
#define NCAT_TILES_ ((B_ * Q_) / 16)    // 6144
#define NNUM_TILES_ ((B_ * P_) / 16)    // 12288
#define GRID_ 1024
#define X0_ (-6.0f)
#define DX_ (12.0f / 128.0f)
#define INVDX_ (128.0f / 12.0f)
#define LN_EPS_ 1e-5f
#define INV_E_ (1.0f / 256.0f)

typedef float vfloat4 __attribute__((ext_vector_type(4)));

__device__ __forceinline__ float gelu_exact(float u) {
    return 0.5f * u * (1.0f + erff(u * 0.70710678118654752f));
}

__device__ __forceinline__ float wave_sum(float x) {
    #pragma unroll
    for (int m = 1; m < 64; m <<= 1) x += __shfl_xor(x, m, 64);
    return x;
}

// LayerNorm one 256-elem row (float4/lane across 64 lanes), nontemporal store.
__device__ __forceinline__ void ln_store(float4 v, float4 g, float4 bt, int e0, int row,
                                         float* __restrict__ out) {
    float mean = wave_sum(v.x + v.y + v.z + v.w) * INV_E_;
    float dx = v.x - mean, dy = v.y - mean, dz = v.z - mean, dw = v.w - mean;
    float s2 = wave_sum(dx * dx + dy * dy + dz * dz + dw * dw);
    float rstd = rsqrtf(s2 * INV_E_ + LN_EPS_);
    vfloat4 o;
    o.x = fmaf(dx * rstd, g.x, bt.x);
    o.y = fmaf(dy * rstd, g.y, bt.y);
    o.z = fmaf(dz * rstd, g.z, bt.z);
    o.w = fmaf(dw * rstd, g.w, bt.w);
    // out is write-once, never re-read: bypass L2 so table/emb stay resident.
    __builtin_nontemporal_store(o, (vfloat4*)&out[(size_t)row * E_ + e0]);
}

// Build one (p, 8-knot) chunk of T[p][k][f].
__device__ __forceinline__ void do_build_chunk(
        int bid, const float* __restrict__ W1, const float* __restrict__ b1,
        const float* __restrict__ W2, const float* __restrict__ b2,
        float* __restrict__ T, float (*h)[E_ + 4]) {
    int p = bid / NKBLK_;
    int k0 = (bid - p * NKBLK_) * KT_;
    int f = threadIdx.x;

    float w = W1[p * E_ + f];
    float b1v = b1[p * E_ + f];
    #pragma unroll
    for (int k = 0; k < KT_; ++k) {
        float x = X0_ + (float)(k0 + k) * DX_;
        h[k][f] = gelu_exact(fmaf(x, w, b1v));
    }
    __syncthreads();

    float acc[KT_];
    float b2v = b2[p * E_ + f];
    #pragma unroll
    for (int k = 0; k < KT_; ++k) acc[k] = b2v;

    const float* W2p = W2 + (size_t)p * E_ * E_ + f;
    for (int e = 0; e < E_; e += 4) {
        float w0 = W2p[(size_t)(e + 0) * E_];
        float w1 = W2p[(size_t)(e + 1) * E_];
        float w2v = W2p[(size_t)(e + 2) * E_];
        float w3 = W2p[(size_t)(e + 3) * E_];
        #pragma unroll
        for (int k = 0; k < KT_; ++k) {
            float4 hv = *(const float4*)&h[k][e];
            acc[k] = fmaf(hv.x, w0, acc[k]);
            acc[k] = fmaf(hv.y, w1, acc[k]);
            acc[k] = fmaf(hv.z, w2v, acc[k]);
            acc[k] = fmaf(hv.w, w3, acc[k]);
        }
    }
    #pragma unroll
    for (int k = 0; k < KT_; ++k) {
        int kk = k0 + k;
        if (kk < NK_) T[((size_t)p * NK_ + kk) * E_ + f] = acc[k];
    }
}

// One cat tile = 16 consecutive cat-rows; this wave does 4 of them.
__device__ __forceinline__ void do_cat_tile(
        int tile, int wv, int lane, const int* __restrict__ x_cat,
        const float* __restrict__ emb, float4 g, float4 bt,
        float* __restrict__ out) {
    int r0 = tile * 16 + wv * 4;           // cat-row index, mult of 4
    int b = r0 / Q_;
    int q0 = r0 - b * Q_;                  // {0,4,8}; 4 rows share b
    int e0 = lane * 4;
    int4 id4 = *(const int4*)&x_cat[b * Q_ + q0];
    int ids[4] = {id4.x, id4.y, id4.z, id4.w};
    float4 v[4];
    #pragma unroll
    for (int j = 0; j < 4; ++j)
        v[j] = *(const float4*)&emb[((size_t)(q0 + j) * V_ + ids[j]) * E_ + e0];
    int orow = b * TOK_ + P_ + q0;
    #pragma unroll
    for (int j = 0; j < 4; ++j) ln_store(v[j], g, bt, e0, orow + j, out);
}

// One num tile = 16 consecutive num-rows; this wave does 4 of them.
__device__ __forceinline__ void do_num_tile(
        int tile, int wv, int lane, const float* __restrict__ T,
        const float* __restrict__ x_num, float4 g, float4 bt,
        float* __restrict__ out) {
    int r0 = tile * 16 + wv * 4;           // num-row index, mult of 4
    int b = r0 / P_;
    int t0 = r0 - b * P_;                  // mult of 4; 4 rows share b
    int e0 = lane * 4;
    float4 x4 = *(const float4*)&x_num[b * P_ + t0];
    float xs[4] = {x4.x, x4.y, x4.z, x4.w};
    const float* bases[4];
    float tts[4];
    #pragma unroll
    for (int j = 0; j < 4; ++j) {
        float s = (xs[j] - X0_) * INVDX_;
        float fi = floorf(s);
        fi = fminf(fmaxf(fi, 0.0f), (float)(NI_ - 1));
        tts[j] = s - fi;                   // unclamped -> linear extrapolation
        bases[j] = T + ((size_t)(t0 + j) * NK_ + (int)fi) * E_ + e0;
    }
    float4 a[4], c[4];
    #pragma unroll
    for (int j = 0; j < 4; ++j) {          // 8 independent loads in flight
        a[j] = *(const float4*)bases[j];
        c[j] = *(const float4*)(bases[j] + E_);
    }
    int orow = b * TOK_ + t0;
    #pragma unroll
    for (int j = 0; j < 4; ++j) {
        float4 v;
        v.x = fmaf(tts[j], c[j].x - a[j].x, a[j].x);
        v.y = fmaf(tts[j], c[j].y - a[j].y, a[j].y);
        v.z = fmaf(tts[j], c[j].z - a[j].z, a[j].z);
        v.w = fmaf(tts[j], c[j].w - a[j].w, a[j].w);
        ln_store(v, g, bt, e0, orow + j, out);
    }
}

// Cooperative mega-kernel: phase1 (build || cat) -> grid sync -> phase2 (num).
__global__ __launch_bounds__(256, 4) void mega(
        const float* __restrict__ W1, const float* __restrict__ b1,
        const float* __restrict__ W2, const float* __restrict__ b2,
        const float* __restrict__ x_num, const int* __restrict__ x_cat,
        const float* __restrict__ emb,
        const float* __restrict__ gamma, const float* __restrict__ beta,
        float* __restrict__ T, float* __restrict__ out) {
    __shared__ float h[KT_][E_ + 4];
    int wv = threadIdx.x >> 6;
    int lane = threadIdx.x & 63;
    int e0 = lane * 4;
    float4 g = *(const float4*)&gamma[e0];
    float4 bt = *(const float4*)&beta[e0];

    if (blockIdx.x < NBUILD_) {
        do_build_chunk(blockIdx.x, W1, b1, W2, b2, T, h);
    } else {
        for (int t = blockIdx.x - NBUILD_; t < NCAT_TILES_; t += gridDim.x - NBUILD_)
            do_cat_tile(t, wv, lane, x_cat, emb, g, bt, out);
    }
    cooperative_groups::this_grid().sync();
    for (int t = blockIdx.x; t < NNUM_TILES_; t += gridDim.x)
        do_num_tile(t, wv, lane, T, x_num, g, bt, out);
}

// ---- Fallback path (no cooperative launch): R5 two-kernel structure ----
__global__ __launch_bounds__(256) void build_and_cat_fb(
        const float* __restrict__ W1, const float* __restrict__ b1,
        const float* __restrict__ W2, const float* __restrict__ b2,
        const int* __restrict__ x_cat, const float* __restrict__ emb,
        const float* __restrict__ gamma, const float* __restrict__ beta,
        float* __restrict__ T, float* __restrict__ out) {
    __shared__ float h[KT_][E_ + 4];
    int wv = threadIdx.x >> 6;
    int lane = threadIdx.x & 63;
    int e0 = lane * 4;
    if (blockIdx.x < NBUILD_) {
        do_build_chunk(blockIdx.x, W1, b1, W2, b2, T, h);
    } else {
        float4 g = *(const float4*)&gamma[e0];
        float4 bt = *(const float4*)&beta[e0];
        do_cat_tile(blockIdx.x - NBUILD_, wv, lane, x_cat, emb, g, bt, out);
    }
}

__global__ __launch_bounds__(256) void fuse_num_fb(
        const float* __restrict__ T, const float* __restrict__ x_num,
        const float* __restrict__ gamma, const float* __restrict__ beta,
        float* __restrict__ out) {
    int wv = threadIdx.x >> 6;
    int lane = threadIdx.x & 63;
    int e0 = lane * 4;
    float4 g = *(const float4*)&gamma[e0];
    float4 bt = *(const float4*)&beta[e0];
    do_num_tile(blockIdx.x, wv, lane, T, x_num, g, bt, out);
}

// Exact fallback (no workspace): direct per-row matvec with in-kernel LN.
__global__ __launch_bounds__(256) void fuse_exact(
        const float* __restrict__ x_num, const int* __restrict__ x_cat,
        const float* __restrict__ W1, const float* __restrict__ b1,
        const float* __restrict__ W2, const float* __restrict__ b2,
        const float* __restrict__ emb,
        const float* __restrict__ gamma, const float* __restrict__ beta,
        float* __restrict__ out) {
    int wv = threadIdx.x >> 6;
    int lane = threadIdx.x & 63;
    int row = blockIdx.x * 4 + wv;
    if (row >= B_ * TOK_) return;
    int b = row / TOK_;
    int t = row - b * TOK_;
    int e0 = lane * 4;
    float4 g = *(const float4*)&gamma[e0];
    float4 bt = *(const float4*)&beta[e0];
    float4 v;
    if (t < P_) {
        float x = x_num[b * P_ + t];
        float4 acc = *(const float4*)&b2[t * E_ + e0];
        for (int e = 0; e < E_; ++e) {
            float he = gelu_exact(fmaf(x, W1[t * E_ + e], b1[t * E_ + e]));
            float4 w = *(const float4*)&W2[((size_t)t * E_ + e) * E_ + e0];
            acc.x = fmaf(he, w.x, acc.x);
            acc.y = fmaf(he, w.y, acc.y);
            acc.z = fmaf(he, w.z, acc.z);
            acc.w = fmaf(he, w.w, acc.w);
        }
        v = acc;
    } else {
        int q = t - P_;
        int idx = x_cat[b * Q_ + q];
        v = *(const float4*)&emb[((size_t)q * V_ + idx) * E_ + e0];
    }
    ln_store(v, g, bt, e0, row, out);
}

extern "C" void kernel_launch(void* const* d_in, const int* in_sizes, int n_in,
                              void* d_out, int out_size, void* d_ws, size_t ws_size,
                              hipStream_t stream) {
    const float* x_num = (const float*)d_in[0];
    const int*   x_cat = (const int*)d_in[1];
    const float* W1    = (const float*)d_in[2];
    const float* b1    = (const float*)d_in[3];
    const float* W2    = (const float*)d_in[4];
    const float* b2    = (const float*)d_in[5];
    const float* emb   = (const float*)d_in[6];
    const float* gamma = (const float*)d_in[7];
    const float* beta  = (const float*)d_in[8];
    float* out = (float*)d_out;

    size_t tbl_bytes = (size_t)P_ * NK_ * E_ * sizeof(float);

    if (ws_size >= tbl_bytes) {
        float* Tbl = (float*)d_ws;
        int coop = 0, dev = 0;
        hipGetDevice(&dev);
        hipDeviceGetAttribute(&coop, hipDeviceAttributeCooperativeLaunch, dev);
        bool done = false;
        if (coop) {
            void* args[] = {(void*)&W1, (void*)&b1, (void*)&W2, (void*)&b2,
                            (void*)&x_num, (void*)&x_cat, (void*)&emb,
                            (void*)&gamma, (void*)&beta, (void*)&Tbl, (void*)&out};
            hipError_t e = hipLaunchCooperativeKernel((const void*)mega, dim3(GRID_),
                                                      dim3(256), args, 0, stream);
            done = (e == hipSuccess);
        }
        if (!done) {
            build_and_cat_fb<<<NBUILD_ + NCAT_TILES_, 256, 0, stream>>>(
                W1, b1, W2, b2, x_cat, emb, gamma, beta, Tbl, out);
            fuse_num_fb<<<NNUM_TILES_, 256, 0, stream>>>(Tbl, x_num, gamma, beta, out);
        }
    } else {
        int nrow_blocks = (B_ * TOK_ + 3) / 4;
        fuse_exact<<<nrow_blocks, 256, 0, stream>>>(x_num, x_cat, W1, b1, W2, b2,
                                                    emb, gamma, beta, out);
    }
}

// Round 9
// 133.221 us; speedup vs baseline: 1.6829x; 1.6829x over previous
//
#include <hip/hip_runtime.h>
#include <hip/hip_bf16.h>
#include <math.h>

#define B_ 8192
#define P_ 24
#define Q_ 12
#define E_ 256
#define V_ 1000
#define TOK_ 36
#define NK_ 129      // knots
#define NI_ 128      // intervals
#define KT_ 8        // knots per build block
#define NKBLK_ 17    // ceil(129/8)
#define NBUILD_ (P_ * NKBLK_)           // 408
#define NCAT_TILES_ ((B_ * Q_) / 16)    // 6144
#define NNUM_TILES_ ((B_ * P_) / 16)    // 12288
#define X0_ (-6.0f)
#define DX_ (12.0f / 128.0f)
#define INVDX_ (128.0f / 12.0f)
#define LN_EPS_ 1e-5f
#define INV_E_ (1.0f / 256.0f)

typedef float vfloat4 __attribute__((ext_vector_type(4)));

__device__ __forceinline__ float gelu_exact(float u) {
    return 0.5f * u * (1.0f + erff(u * 0.70710678118654752f));
}

// ---- build table T[p][k][f] (unchanged from R5) ----
__device__ __forceinline__ void do_build_chunk(
        int bid, const float* __restrict__ W1, const float* __restrict__ b1,
        const float* __restrict__ W2, const float* __restrict__ b2,
        float* __restrict__ T, float (*h)[E_ + 4]) {
    int p = bid / NKBLK_;
    int k0 = (bid - p * NKBLK_) * KT_;
    int f = threadIdx.x;

    float w = W1[p * E_ + f];
    float b1v = b1[p * E_ + f];
    #pragma unroll
    for (int k = 0; k < KT_; ++k) {
        float x = X0_ + (float)(k0 + k) * DX_;
        h[k][f] = gelu_exact(fmaf(x, w, b1v));
    }
    __syncthreads();

    float acc[KT_];
    float b2v = b2[p * E_ + f];
    #pragma unroll
    for (int k = 0; k < KT_; ++k) acc[k] = b2v;

    const float* W2p = W2 + (size_t)p * E_ * E_ + f;
    for (int e = 0; e < E_; e += 4) {
        float w0 = W2p[(size_t)(e + 0) * E_];
        float w1 = W2p[(size_t)(e + 1) * E_];
        float w2v = W2p[(size_t)(e + 2) * E_];
        float w3 = W2p[(size_t)(e + 3) * E_];
        #pragma unroll
        for (int k = 0; k < KT_; ++k) {
            float4 hv = *(const float4*)&h[k][e];
            acc[k] = fmaf(hv.x, w0, acc[k]);
            acc[k] = fmaf(hv.y, w1, acc[k]);
            acc[k] = fmaf(hv.z, w2v, acc[k]);
            acc[k] = fmaf(hv.w, w3, acc[k]);
        }
    }
    #pragma unroll
    for (int k = 0; k < KT_; ++k) {
        int kk = k0 + k;
        if (kk < NK_) T[((size_t)p * NK_ + kk) * E_ + f] = acc[k];
    }
}

// 16-lane-group LN + store: lane = 16*r + c holds elems [c*16, c*16+16) of row r's
// group. Reductions use only xor 1/2/4/8 (DPP row-ops, no LDS-latency steps).
// Variance via E[x^2] - mean^2 (validated in R7, same absmax).
__device__ __forceinline__ void ln16_store(
        const float4 v[4], const float4 gg[4], const float4 bb[4],
        int c, int row, float* __restrict__ out) {
    float s1 = 0.f, ss = 0.f;
    #pragma unroll
    for (int j = 0; j < 4; ++j) {
        s1 += v[j].x + v[j].y + v[j].z + v[j].w;
        ss += v[j].x * v[j].x + v[j].y * v[j].y + v[j].z * v[j].z + v[j].w * v[j].w;
    }
    #pragma unroll
    for (int m = 1; m < 16; m <<= 1) {
        s1 += __shfl_xor(s1, m, 64);
        ss += __shfl_xor(ss, m, 64);
    }
    float mean = s1 * INV_E_;
    float var = fmaxf(ss * INV_E_ - mean * mean, 0.0f);
    float rstd = rsqrtf(var + LN_EPS_);
    float* orow = out + (size_t)row * E_ + c * 16;
    #pragma unroll
    for (int j = 0; j < 4; ++j) {
        float4 o;
        o.x = fmaf((v[j].x - mean) * rstd, gg[j].x, bb[j].x);
        o.y = fmaf((v[j].y - mean) * rstd, gg[j].y, bb[j].y);
        o.z = fmaf((v[j].z - mean) * rstd, gg[j].z, bb[j].z);
        o.w = fmaf((v[j].w - mean) * rstd, gg[j].w, bb[j].w);
        *(float4*)(orow + j * 4) = o;   // normal store: L2 coalesces the 64B-stride pattern
    }
}

// One cat tile = 16 cat-rows; wave does 4 (one per 16-lane group).
__device__ __forceinline__ void do_cat_tile(
        int tile, int wv, int r, int c, const int* __restrict__ x_cat,
        const float* __restrict__ emb, const float4 gg[4], const float4 bb[4],
        float* __restrict__ out) {
    int r0 = tile * 16 + wv * 4;
    int b = r0 / Q_;
    int q0 = r0 - b * Q_;                  // {0,4,8}
    int4 id4 = *(const int4*)&x_cat[b * Q_ + q0];   // broadcast
    int idx = (r == 0) ? id4.x : (r == 1) ? id4.y : (r == 2) ? id4.z : id4.w;
    const float* erow = emb + ((size_t)(q0 + r) * V_ + idx) * E_ + c * 16;
    float4 v[4];
    #pragma unroll
    for (int j = 0; j < 4; ++j) v[j] = *(const float4*)(erow + j * 4);
    ln16_store(v, gg, bb, c, b * TOK_ + P_ + q0 + r, out);
}

// One num tile = 16 num-rows; wave does 4 (one per 16-lane group).
__device__ __forceinline__ void do_num_tile(
        int tile, int wv, int r, int c, const float* __restrict__ T,
        const float* __restrict__ x_num, const float4 gg[4], const float4 bb[4],
        float* __restrict__ out) {
    int r0 = tile * 16 + wv * 4;
    int b = r0 / P_;
    int t0 = r0 - b * P_;                  // mult of 4
    float4 x4 = *(const float4*)&x_num[b * P_ + t0];   // broadcast, 16B-aligned
    float x = (r == 0) ? x4.x : (r == 1) ? x4.y : (r == 2) ? x4.z : x4.w;
    float s = (x - X0_) * INVDX_;
    float fi = floorf(s);
    fi = fminf(fmaxf(fi, 0.0f), (float)(NI_ - 1));
    float t = s - fi;                      // unclamped -> linear extrapolation
    int p = t0 + r;
    const float* rowa = T + ((size_t)p * NK_ + (int)fi) * E_ + c * 16;
    float4 a[4], cc[4];
    #pragma unroll
    for (int j = 0; j < 4; ++j) {          // 8 independent 16B loads in flight
        a[j] = *(const float4*)(rowa + j * 4);
        cc[j] = *(const float4*)(rowa + E_ + j * 4);
    }
    float4 v[4];
    #pragma unroll
    for (int j = 0; j < 4; ++j) {
        v[j].x = fmaf(t, cc[j].x - a[j].x, a[j].x);
        v[j].y = fmaf(t, cc[j].y - a[j].y, a[j].y);
        v[j].z = fmaf(t, cc[j].z - a[j].z, a[j].z);
        v[j].w = fmaf(t, cc[j].w - a[j].w, a[j].w);
    }
    ln16_store(v, gg, bb, c, b * TOK_ + t0 + r, out);
}

// K1: blocks [0,408) build the table; blocks [408,408+6144) do all cat tokens.
// Independent halves overlap: cat waves' memory pressure hides build latency.
__global__ __launch_bounds__(256) void build_and_cat(
        const float* __restrict__ W1, const float* __restrict__ b1,
        const float* __restrict__ W2, const float* __restrict__ b2,
        const int* __restrict__ x_cat, const float* __restrict__ emb,
        const float* __restrict__ gamma, const float* __restrict__ beta,
        float* __restrict__ T, float* __restrict__ out) {
    __shared__ float h[KT_][E_ + 4];
    if (blockIdx.x < NBUILD_) {
        do_build_chunk(blockIdx.x, W1, b1, W2, b2, T, h);
    } else {
        int wv = threadIdx.x >> 6;
        int lane = threadIdx.x & 63;
        int r = lane >> 4, c = lane & 15;
        float4 gg[4], bb[4];
        #pragma unroll
        for (int j = 0; j < 4; ++j) {
            gg[j] = *(const float4*)&gamma[c * 16 + j * 4];
            bb[j] = *(const float4*)&beta[c * 16 + j * 4];
        }
        do_cat_tile(blockIdx.x - NBUILD_, wv, r, c, x_cat, emb, gg, bb, out);
    }
}

// K2: all numeric tokens via table interpolation (table L2-hot).
__global__ __launch_bounds__(256) void fuse_num(
        const float* __restrict__ T, const float* __restrict__ x_num,
        const float* __restrict__ gamma, const float* __restrict__ beta,
        float* __restrict__ out) {
    int wv = threadIdx.x >> 6;
    int lane = threadIdx.x & 63;
    int r = lane >> 4, c = lane & 15;
    float4 gg[4], bb[4];
    #pragma unroll
    for (int j = 0; j < 4; ++j) {
        gg[j] = *(const float4*)&gamma[c * 16 + j * 4];
        bb[j] = *(const float4*)&beta[c * 16 + j * 4];
    }
    do_num_tile(blockIdx.x, wv, r, c, T, x_num, gg, bb, out);
}

// Exact fallback (no workspace): direct per-row matvec with 64-lane LN.
__global__ __launch_bounds__(256) void fuse_exact(
        const float* __restrict__ x_num, const int* __restrict__ x_cat,
        const float* __restrict__ W1, const float* __restrict__ b1,
        const float* __restrict__ W2, const float* __restrict__ b2,
        const float* __restrict__ emb,
        const float* __restrict__ gamma, const float* __restrict__ beta,
        float* __restrict__ out) {
    int wv = threadIdx.x >> 6;
    int lane = threadIdx.x & 63;
    int row = blockIdx.x * 4 + wv;
    if (row >= B_ * TOK_) return;
    int b = row / TOK_;
    int t = row - b * TOK_;
    int e0 = lane * 4;
    float4 g = *(const float4*)&gamma[e0];
    float4 bt = *(const float4*)&beta[e0];
    float4 v;
    if (t < P_) {
        float x = x_num[b * P_ + t];
        float4 acc = *(const float4*)&b2[t * E_ + e0];
        for (int e = 0; e < E_; ++e) {
            float he = gelu_exact(fmaf(x, W1[t * E_ + e], b1[t * E_ + e]));
            float4 w = *(const float4*)&W2[((size_t)t * E_ + e) * E_ + e0];
            acc.x = fmaf(he, w.x, acc.x);
            acc.y = fmaf(he, w.y, acc.y);
            acc.z = fmaf(he, w.z, acc.z);
            acc.w = fmaf(he, w.w, acc.w);
        }
        v = acc;
    } else {
        int q = t - P_;
        int idx = x_cat[b * Q_ + q];
        v = *(const float4*)&emb[((size_t)q * V_ + idx) * E_ + e0];
    }
    float s1 = v.x + v.y + v.z + v.w;
    #pragma unroll
    for (int m = 1; m < 64; m <<= 1) s1 += __shfl_xor(s1, m, 64);
    float mean = s1 * INV_E_;
    float dx = v.x - mean, dy = v.y - mean, dz = v.z - mean, dw = v.w - mean;
    float s2 = dx * dx + dy * dy + dz * dz + dw * dw;
    #pragma unroll
    for (int m = 1; m < 64; m <<= 1) s2 += __shfl_xor(s2, m, 64);
    float rstd = rsqrtf(s2 * INV_E_ + LN_EPS_);
    float4 o;
    o.x = fmaf(dx * rstd, g.x, bt.x);
    o.y = fmaf(dy * rstd, g.y, bt.y);
    o.z = fmaf(dz * rstd, g.z, bt.z);
    o.w = fmaf(dw * rstd, g.w, bt.w);
    *(float4*)&out[(size_t)row * E_ + e0] = o;
}

extern "C" void kernel_launch(void* const* d_in, const int* in_sizes, int n_in,
                              void* d_out, int out_size, void* d_ws, size_t ws_size,
                              hipStream_t stream) {
    const float* x_num = (const float*)d_in[0];
    const int*   x_cat = (const int*)d_in[1];
    const float* W1    = (const float*)d_in[2];
    const float* b1    = (const float*)d_in[3];
    const float* W2    = (const float*)d_in[4];
    const float* b2    = (const float*)d_in[5];
    const float* emb   = (const float*)d_in[6];
    const float* gamma = (const float*)d_in[7];
    const float* beta  = (const float*)d_in[8];
    float* out = (float*)d_out;

    size_t tbl_bytes = (size_t)P_ * NK_ * E_ * sizeof(float);

    if (ws_size >= tbl_bytes) {
        float* Tbl = (float*)d_ws;
        build_and_cat<<<NBUILD_ + NCAT_TILES_, 256, 0, stream>>>(
            W1, b1, W2, b2, x_cat, emb, gamma, beta, Tbl, out);
        fuse_num<<<NNUM_TILES_, 256, 0, stream>>>(Tbl, x_num, gamma, beta, out);
    } else {
        int nrow_blocks = (B_ * TOK_ + 3) / 4;
        fuse_exact<<<nrow_blocks, 256, 0, stream>>>(x_num, x_cat, W1, b1, W2, b2,
                                                    emb, gamma, beta, out);
    }
}

// Round 10
// 76.126 us; speedup vs baseline: 2.9452x; 1.7500x over previous
//
#include <hip/hip_runtime.h>
#include <hip/hip_fp16.h>
#include <math.h>

#define B_ 8192
#define P_ 24
#define Q_ 12
#define E_ 256
#define V_ 1000
#define TOK_ 36
#define NI_ 128      // intervals
#define KT_ 8        // intervals per build block
#define NKBLK_ 16    // 128/8
#define NBUILD_ (P_ * NKBLK_)           // 384
#define NCAT_TILES_ ((B_ * Q_) / 16)    // 6144
#define NNUM_TILES_ ((B_ * P_) / 16)    // 12288
#define X0_ (-6.0f)
#define DX_ (12.0f / 128.0f)
#define INVDX_ (128.0f / 12.0f)
#define LN_EPS_ 1e-5f
#define INV_E_ (1.0f / 256.0f)

typedef float vfloat4 __attribute__((ext_vector_type(4)));

__device__ __forceinline__ float gelu_exact(float u) {
    return 0.5f * u * (1.0f + erff(u * 0.70710678118654752f));
}

// Build packed interval table T2[p][i][f] = half2(a, d) where a = F_p(x_i)[f],
// d = F_p(x_{i+1})[f] - a. Each block computes KT_+1 = 9 knots -> 8 intervals.
__device__ __forceinline__ void do_build_chunk(
        int bid, const float* __restrict__ W1, const float* __restrict__ b1,
        const float* __restrict__ W2, const float* __restrict__ b2,
        __half2* __restrict__ T2, float (*h)[E_ + 4]) {
    int p = bid / NKBLK_;
    int k0 = (bid - p * NKBLK_) * KT_;
    int f = threadIdx.x;

    float w = W1[p * E_ + f];
    float b1v = b1[p * E_ + f];
    #pragma unroll
    for (int k = 0; k < KT_ + 1; ++k) {
        float x = X0_ + (float)(k0 + k) * DX_;
        h[k][f] = gelu_exact(fmaf(x, w, b1v));
    }
    __syncthreads();

    float acc[KT_ + 1];
    float b2v = b2[p * E_ + f];
    #pragma unroll
    for (int k = 0; k < KT_ + 1; ++k) acc[k] = b2v;

    const float* W2p = W2 + (size_t)p * E_ * E_ + f;
    for (int e = 0; e < E_; e += 4) {
        float w0 = W2p[(size_t)(e + 0) * E_];
        float w1 = W2p[(size_t)(e + 1) * E_];
        float w2v = W2p[(size_t)(e + 2) * E_];
        float w3 = W2p[(size_t)(e + 3) * E_];
        #pragma unroll
        for (int k = 0; k < KT_ + 1; ++k) {
            float4 hv = *(const float4*)&h[k][e];
            acc[k] = fmaf(hv.x, w0, acc[k]);
            acc[k] = fmaf(hv.y, w1, acc[k]);
            acc[k] = fmaf(hv.z, w2v, acc[k]);
            acc[k] = fmaf(hv.w, w3, acc[k]);
        }
    }
    #pragma unroll
    for (int k = 0; k < KT_; ++k) {
        int i = k0 + k;
        T2[((size_t)p * NI_ + i) * E_ + f] =
            __floats2half2_rn(acc[k], acc[k + 1] - acc[k]);  // (a, d) packed
    }
}

// LayerNorm one 256-elem row (float4/lane across 64 lanes), nontemporal store.
__device__ __forceinline__ void ln_store(float4 v, float4 g, float4 bt, int e0, int row,
                                         float* __restrict__ out) {
    float s1 = v.x + v.y + v.z + v.w;
    #pragma unroll
    for (int m = 1; m < 64; m <<= 1) s1 += __shfl_xor(s1, m, 64);
    float mean = s1 * INV_E_;
    float dx = v.x - mean, dy = v.y - mean, dz = v.z - mean, dw = v.w - mean;
    float s2 = dx * dx + dy * dy + dz * dz + dw * dw;
    #pragma unroll
    for (int m = 1; m < 64; m <<= 1) s2 += __shfl_xor(s2, m, 64);
    float rstd = rsqrtf(s2 * INV_E_ + LN_EPS_);
    vfloat4 o;
    o.x = fmaf(dx * rstd, g.x, bt.x);
    o.y = fmaf(dy * rstd, g.y, bt.y);
    o.z = fmaf(dz * rstd, g.z, bt.z);
    o.w = fmaf(dw * rstd, g.w, bt.w);
    // out is write-once, never re-read: bypass L2 so table/emb stay resident.
    __builtin_nontemporal_store(o, (vfloat4*)&out[(size_t)row * E_ + e0]);
}

// One cat tile = 16 consecutive cat-rows; this wave does 4 (R5 layout).
__device__ __forceinline__ void do_cat_tile(
        int tile, int wv, int lane, const int* __restrict__ x_cat,
        const float* __restrict__ emb, float4 g, float4 bt,
        float* __restrict__ out) {
    int r0 = tile * 16 + wv * 4;           // cat-row index, mult of 4
    int b = r0 / Q_;
    int q0 = r0 - b * Q_;                  // {0,4,8}; 4 rows share b
    int e0 = lane * 4;
    int4 id4 = *(const int4*)&x_cat[b * Q_ + q0];
    int ids[4] = {id4.x, id4.y, id4.z, id4.w};
    float4 v[4];
    #pragma unroll
    for (int j = 0; j < 4; ++j)
        v[j] = *(const float4*)&emb[((size_t)(q0 + j) * V_ + ids[j]) * E_ + e0];
    int orow = b * TOK_ + P_ + q0;
    #pragma unroll
    for (int j = 0; j < 4; ++j) ln_store(v[j], g, bt, e0, orow + j, out);
}

// One num tile = 16 consecutive num-rows; this wave does 4. Packed-table path:
// ONE 16B load per row (4 half2 = 4 elems of (a,d)) instead of two fp32 loads.
__device__ __forceinline__ void do_num_tile(
        int tile, int wv, int lane, const __half2* __restrict__ T2,
        const float* __restrict__ x_num, float4 g, float4 bt,
        float* __restrict__ out) {
    int r0 = tile * 16 + wv * 4;           // num-row index, mult of 4
    int b = r0 / P_;
    int t0 = r0 - b * P_;                  // mult of 4; 4 rows share b
    int e0 = lane * 4;
    float4 x4 = *(const float4*)&x_num[b * P_ + t0];   // broadcast, 16B-aligned
    float xs[4] = {x4.x, x4.y, x4.z, x4.w};
    const __half2* bases[4];
    float tts[4];
    #pragma unroll
    for (int j = 0; j < 4; ++j) {
        float s = (xs[j] - X0_) * INVDX_;
        float fi = floorf(s);
        fi = fminf(fmaxf(fi, 0.0f), (float)(NI_ - 1));
        tts[j] = s - fi;                   // unclamped -> linear extrapolation
        bases[j] = T2 + ((size_t)(t0 + j) * NI_ + (int)fi) * E_ + e0;
    }
    float4 raw[4];
    #pragma unroll
    for (int j = 0; j < 4; ++j)            // 4 independent 16B loads in flight
        raw[j] = *(const float4*)bases[j];
    int orow = b * TOK_ + t0;
    #pragma unroll
    for (int j = 0; j < 4; ++j) {
        const __half2* hp = (const __half2*)&raw[j];
        float2 p0 = __half22float2(hp[0]);
        float2 p1 = __half22float2(hp[1]);
        float2 p2 = __half22float2(hp[2]);
        float2 p3 = __half22float2(hp[3]);
        float4 v;
        v.x = fmaf(tts[j], p0.y, p0.x);
        v.y = fmaf(tts[j], p1.y, p1.x);
        v.z = fmaf(tts[j], p2.y, p2.x);
        v.w = fmaf(tts[j], p3.y, p3.x);
        ln_store(v, g, bt, e0, orow + j, out);
    }
}

// K1: blocks [0,384) build the packed table; blocks [384,384+6144) do all cat
// tokens. Independent halves overlap: cat memory pressure hides build latency.
__global__ __launch_bounds__(256) void build_and_cat(
        const float* __restrict__ W1, const float* __restrict__ b1,
        const float* __restrict__ W2, const float* __restrict__ b2,
        const int* __restrict__ x_cat, const float* __restrict__ emb,
        const float* __restrict__ gamma, const float* __restrict__ beta,
        __half2* __restrict__ T2, float* __restrict__ out) {
    __shared__ float h[KT_ + 1][E_ + 4];
    if (blockIdx.x < NBUILD_) {
        do_build_chunk(blockIdx.x, W1, b1, W2, b2, T2, h);
    } else {
        int wv = threadIdx.x >> 6;
        int lane = threadIdx.x & 63;
        int e0 = lane * 4;
        float4 g = *(const float4*)&gamma[e0];
        float4 bt = *(const float4*)&beta[e0];
        do_cat_tile(blockIdx.x - NBUILD_, wv, lane, x_cat, emb, g, bt, out);
    }
}

// K2: all numeric tokens via packed-table interpolation (table L2-hot, 3.15 MB).
__global__ __launch_bounds__(256) void fuse_num(
        const __half2* __restrict__ T2, const float* __restrict__ x_num,
        const float* __restrict__ gamma, const float* __restrict__ beta,
        float* __restrict__ out) {
    int wv = threadIdx.x >> 6;
    int lane = threadIdx.x & 63;
    int e0 = lane * 4;
    float4 g = *(const float4*)&gamma[e0];
    float4 bt = *(const float4*)&beta[e0];
    do_num_tile(blockIdx.x, wv, lane, T2, x_num, g, bt, out);
}

// Exact fallback (no workspace): direct per-row matvec with 64-lane LN.
__global__ __launch_bounds__(256) void fuse_exact(
        const float* __restrict__ x_num, const int* __restrict__ x_cat,
        const float* __restrict__ W1, const float* __restrict__ b1,
        const float* __restrict__ W2, const float* __restrict__ b2,
        const float* __restrict__ emb,
        const float* __restrict__ gamma, const float* __restrict__ beta,
        float* __restrict__ out) {
    int wv = threadIdx.x >> 6;
    int lane = threadIdx.x & 63;
    int row = blockIdx.x * 4 + wv;
    if (row >= B_ * TOK_) return;
    int b = row / TOK_;
    int t = row - b * TOK_;
    int e0 = lane * 4;
    float4 g = *(const float4*)&gamma[e0];
    float4 bt = *(const float4*)&beta[e0];
    float4 v;
    if (t < P_) {
        float x = x_num[b * P_ + t];
        float4 acc = *(const float4*)&b2[t * E_ + e0];
        for (int e = 0; e < E_; ++e) {
            float he = gelu_exact(fmaf(x, W1[t * E_ + e], b1[t * E_ + e]));
            float4 w = *(const float4*)&W2[((size_t)t * E_ + e) * E_ + e0];
            acc.x = fmaf(he, w.x, acc.x);
            acc.y = fmaf(he, w.y, acc.y);
            acc.z = fmaf(he, w.z, acc.z);
            acc.w = fmaf(he, w.w, acc.w);
        }
        v = acc;
    } else {
        int q = t - P_;
        int idx = x_cat[b * Q_ + q];
        v = *(const float4*)&emb[((size_t)q * V_ + idx) * E_ + e0];
    }
    ln_store(v, g, bt, e0, row, out);
}

extern "C" void kernel_launch(void* const* d_in, const int* in_sizes, int n_in,
                              void* d_out, int out_size, void* d_ws, size_t ws_size,
                              hipStream_t stream) {
    const float* x_num = (const float*)d_in[0];
    const int*   x_cat = (const int*)d_in[1];
    const float* W1    = (const float*)d_in[2];
    const float* b1    = (const float*)d_in[3];
    const float* W2    = (const float*)d_in[4];
    const float* b2    = (const float*)d_in[5];
    const float* emb   = (const float*)d_in[6];
    const float* gamma = (const float*)d_in[7];
    const float* beta  = (const float*)d_in[8];
    float* out = (float*)d_out;

    size_t tbl_bytes = (size_t)P_ * NI_ * E_ * sizeof(__half2);   // 3.15 MB

    if (ws_size >= tbl_bytes) {
        __half2* T2 = (__half2*)d_ws;
        build_and_cat<<<NBUILD_ + NCAT_TILES_, 256, 0, stream>>>(
            W1, b1, W2, b2, x_cat, emb, gamma, beta, T2, out);
        fuse_num<<<NNUM_TILES_, 256, 0, stream>>>(T2, x_num, gamma, beta, out);
    } else {
        int nrow_blocks = (B_ * TOK_ + 3) / 4;
        fuse_exact<<<nrow_blocks, 256, 0, stream>>>(x_num, x_cat, W1, b1, W2, b2,
                                                    emb, gamma, beta, out);
    }
}

// Round 11
// 74.781 us; speedup vs baseline: 2.9982x; 1.0180x over previous
//
#include <hip/hip_runtime.h>
#include <hip/hip_fp16.h>
#include <math.h>

#define B_ 8192
#define P_ 24
#define Q_ 12
#define E_ 256
#define V_ 1000
#define TOK_ 36
#define NI_ 128      // intervals
#define KT_ 8        // intervals per build block
#define NKBLK_ 16    // 128/8
#define NBUILD_ (P_ * NKBLK_)           // 384
#define NCAT_TILES_ (Q_ * (B_ / 16))    // 6144: (q, 16-b chunk)
#define NNUM_TILES_ ((B_ * P_) / 16)    // 12288
#define X0_ (-6.0f)
#define DX_ (12.0f / 128.0f)
#define INVDX_ (128.0f / 12.0f)
#define LN_EPS_ 1e-5f
#define INV_E_ (1.0f / 256.0f)

typedef float vfloat4 __attribute__((ext_vector_type(4)));

__device__ __forceinline__ float gelu_exact(float u) {
    return 0.5f * u * (1.0f + erff(u * 0.70710678118654752f));
}

// Build packed interval table T2[p][i][f] = half2(a, d): a = F_p(x_i)[f],
// d = F_p(x_{i+1})[f] - a. Each block computes 9 knots -> 8 intervals.
__device__ __forceinline__ void do_build_chunk(
        int bid, const float* __restrict__ W1, const float* __restrict__ b1,
        const float* __restrict__ W2, const float* __restrict__ b2,
        __half2* __restrict__ T2, float (*h)[E_ + 4]) {
    int p = bid / NKBLK_;
    int k0 = (bid - p * NKBLK_) * KT_;
    int f = threadIdx.x;

    float w = W1[p * E_ + f];
    float b1v = b1[p * E_ + f];
    #pragma unroll
    for (int k = 0; k < KT_ + 1; ++k) {
        float x = X0_ + (float)(k0 + k) * DX_;
        h[k][f] = gelu_exact(fmaf(x, w, b1v));
    }
    __syncthreads();

    float acc[KT_ + 1];
    float b2v = b2[p * E_ + f];
    #pragma unroll
    for (int k = 0; k < KT_ + 1; ++k) acc[k] = b2v;

    const float* W2p = W2 + (size_t)p * E_ * E_ + f;
    for (int e = 0; e < E_; e += 4) {
        float w0 = W2p[(size_t)(e + 0) * E_];
        float w1 = W2p[(size_t)(e + 1) * E_];
        float w2v = W2p[(size_t)(e + 2) * E_];
        float w3 = W2p[(size_t)(e + 3) * E_];
        #pragma unroll
        for (int k = 0; k < KT_ + 1; ++k) {
            float4 hv = *(const float4*)&h[k][e];
            acc[k] = fmaf(hv.x, w0, acc[k]);
            acc[k] = fmaf(hv.y, w1, acc[k]);
            acc[k] = fmaf(hv.z, w2v, acc[k]);
            acc[k] = fmaf(hv.w, w3, acc[k]);
        }
    }
    #pragma unroll
    for (int k = 0; k < KT_; ++k) {
        int i = k0 + k;
        T2[((size_t)p * NI_ + i) * E_ + f] =
            __floats2half2_rn(acc[k], acc[k + 1] - acc[k]);  // (a, d) packed
    }
}

// LayerNorm one 256-elem row (float4/lane across 64 lanes), nontemporal store.
__device__ __forceinline__ void ln_store(float4 v, float4 g, float4 bt, int e0, int row,
                                         float* __restrict__ out) {
    float s1 = v.x + v.y + v.z + v.w;
    #pragma unroll
    for (int m = 1; m < 64; m <<= 1) s1 += __shfl_xor(s1, m, 64);
    float mean = s1 * INV_E_;
    float dx = v.x - mean, dy = v.y - mean, dz = v.z - mean, dw = v.w - mean;
    float s2 = dx * dx + dy * dy + dz * dz + dw * dw;
    #pragma unroll
    for (int m = 1; m < 64; m <<= 1) s2 += __shfl_xor(s2, m, 64);
    float rstd = rsqrtf(s2 * INV_E_ + LN_EPS_);
    vfloat4 o;
    o.x = fmaf(dx * rstd, g.x, bt.x);
    o.y = fmaf(dy * rstd, g.y, bt.y);
    o.z = fmaf(dz * rstd, g.z, bt.z);
    o.w = fmaf(dw * rstd, g.w, bt.w);
    // out is write-once, never re-read: bypass L2 so table/emb stay resident.
    __builtin_nontemporal_store(o, (vfloat4*)&out[(size_t)row * E_ + e0]);
}

// q-major cat tile: one q, 16 consecutive b's. 512 consecutive blocks share one
// q -> its 1.02 MB emb slab is L2-resident on every XCD. Wave does 4 b's.
__device__ __forceinline__ void do_cat_tile(
        int ct, int wv, int lane, const int* __restrict__ x_cat,
        const float* __restrict__ emb, float4 g, float4 bt,
        float* __restrict__ out) {
    int q = ct >> 9;                       // ct / 512
    int b0 = (ct & 511) * 16 + wv * 4;     // 4 consecutive b's for this wave
    int e0 = lane * 4;
    const float* eq = emb + (size_t)q * V_ * E_;
    int ids[4];
    #pragma unroll
    for (int j = 0; j < 4; ++j) ids[j] = x_cat[(b0 + j) * Q_ + q];
    float4 v[4];
    #pragma unroll
    for (int j = 0; j < 4; ++j)            // 4 independent gathers in flight
        v[j] = *(const float4*)&eq[(size_t)ids[j] * E_ + e0];
    #pragma unroll
    for (int j = 0; j < 4; ++j)
        ln_store(v[j], g, bt, e0, (b0 + j) * TOK_ + P_ + q, out);
}

// One num tile = 16 consecutive num-rows; this wave does 4. Packed-table path:
// ONE 16B load per row (4 x half2(a,d)) instead of two fp32 loads.
__device__ __forceinline__ void do_num_tile(
        int tile, int wv, int lane, const __half2* __restrict__ T2,
        const float* __restrict__ x_num, float4 g, float4 bt,
        float* __restrict__ out) {
    int r0 = tile * 16 + wv * 4;           // num-row index, mult of 4
    int b = r0 / P_;
    int t0 = r0 - b * P_;                  // mult of 4; 4 rows share b
    int e0 = lane * 4;
    float4 x4 = *(const float4*)&x_num[b * P_ + t0];   // broadcast, 16B-aligned
    float xs[4] = {x4.x, x4.y, x4.z, x4.w};
    const __half2* bases[4];
    float tts[4];
    #pragma unroll
    for (int j = 0; j < 4; ++j) {
        float s = (xs[j] - X0_) * INVDX_;
        float fi = floorf(s);
        fi = fminf(fmaxf(fi, 0.0f), (float)(NI_ - 1));
        tts[j] = s - fi;                   // unclamped -> linear extrapolation
        bases[j] = T2 + ((size_t)(t0 + j) * NI_ + (int)fi) * E_ + e0;
    }
    float4 raw[4];
    #pragma unroll
    for (int j = 0; j < 4; ++j)            // 4 independent 16B loads in flight
        raw[j] = *(const float4*)bases[j];
    int orow = b * TOK_ + t0;
    #pragma unroll
    for (int j = 0; j < 4; ++j) {
        const __half2* hp = (const __half2*)&raw[j];
        float2 p0 = __half22float2(hp[0]);
        float2 p1 = __half22float2(hp[1]);
        float2 p2 = __half22float2(hp[2]);
        float2 p3 = __half22float2(hp[3]);
        float4 v;
        v.x = fmaf(tts[j], p0.y, p0.x);
        v.y = fmaf(tts[j], p1.y, p1.x);
        v.z = fmaf(tts[j], p2.y, p2.x);
        v.w = fmaf(tts[j], p3.y, p3.x);
        ln_store(v, g, bt, e0, orow + j, out);
    }
}

// K1: blocks [0,384) build the packed table; blocks [384,384+6144) do all cat
// tokens q-major. Independent halves overlap; cat hides build latency.
__global__ __launch_bounds__(256) void build_and_cat(
        const float* __restrict__ W1, const float* __restrict__ b1,
        const float* __restrict__ W2, const float* __restrict__ b2,
        const int* __restrict__ x_cat, const float* __restrict__ emb,
        const float* __restrict__ gamma, const float* __restrict__ beta,
        __half2* __restrict__ T2, float* __restrict__ out) {
    __shared__ float h[KT_ + 1][E_ + 4];
    if (blockIdx.x < NBUILD_) {
        do_build_chunk(blockIdx.x, W1, b1, W2, b2, T2, h);
    } else {
        int wv = threadIdx.x >> 6;
        int lane = threadIdx.x & 63;
        int e0 = lane * 4;
        float4 g = *(const float4*)&gamma[e0];
        float4 bt = *(const float4*)&beta[e0];
        do_cat_tile(blockIdx.x - NBUILD_, wv, lane, x_cat, emb, g, bt, out);
    }
}

// K2: all numeric tokens via packed-table interpolation (table L2-hot, 3.15 MB).
__global__ __launch_bounds__(256) void fuse_num(
        const __half2* __restrict__ T2, const float* __restrict__ x_num,
        const float* __restrict__ gamma, const float* __restrict__ beta,
        float* __restrict__ out) {
    int wv = threadIdx.x >> 6;
    int lane = threadIdx.x & 63;
    int e0 = lane * 4;
    float4 g = *(const float4*)&gamma[e0];
    float4 bt = *(const float4*)&beta[e0];
    do_num_tile(blockIdx.x, wv, lane, T2, x_num, g, bt, out);
}

// Exact fallback (no workspace): direct per-row matvec with 64-lane LN.
__global__ __launch_bounds__(256) void fuse_exact(
        const float* __restrict__ x_num, const int* __restrict__ x_cat,
        const float* __restrict__ W1, const float* __restrict__ b1,
        const float* __restrict__ W2, const float* __restrict__ b2,
        const float* __restrict__ emb,
        const float* __restrict__ gamma, const float* __restrict__ beta,
        float* __restrict__ out) {
    int wv = threadIdx.x >> 6;
    int lane = threadIdx.x & 63;
    int row = blockIdx.x * 4 + wv;
    if (row >= B_ * TOK_) return;
    int b = row / TOK_;
    int t = row - b * TOK_;
    int e0 = lane * 4;
    float4 g = *(const float4*)&gamma[e0];
    float4 bt = *(const float4*)&beta[e0];
    float4 v;
    if (t < P_) {
        float x = x_num[b * P_ + t];
        float4 acc = *(const float4*)&b2[t * E_ + e0];
        for (int e = 0; e < E_; ++e) {
            float he = gelu_exact(fmaf(x, W1[t * E_ + e], b1[t * E_ + e]));
            float4 w = *(const float4*)&W2[((size_t)t * E_ + e) * E_ + e0];
            acc.x = fmaf(he, w.x, acc.x);
            acc.y = fmaf(he, w.y, acc.y);
            acc.z = fmaf(he, w.z, acc.z);
            acc.w = fmaf(he, w.w, acc.w);
        }
        v = acc;
    } else {
        int q = t - P_;
        int idx = x_cat[b * Q_ + q];
        v = *(const float4*)&emb[((size_t)q * V_ + idx) * E_ + e0];
    }
    ln_store(v, g, bt, e0, row, out);
}

extern "C" void kernel_launch(void* const* d_in, const int* in_sizes, int n_in,
                              void* d_out, int out_size, void* d_ws, size_t ws_size,
                              hipStream_t stream) {
    const float* x_num = (const float*)d_in[0];
    const int*   x_cat = (const int*)d_in[1];
    const float* W1    = (const float*)d_in[2];
    const float* b1    = (const float*)d_in[3];
    const float* W2    = (const float*)d_in[4];
    const float* b2    = (const float*)d_in[5];
    const float* emb   = (const float*)d_in[6];
    const float* gamma = (const float*)d_in[7];
    const float* beta  = (const float*)d_in[8];
    float* out = (float*)d_out;

    size_t tbl_bytes = (size_t)P_ * NI_ * E_ * sizeof(__half2);   // 3.15 MB

    if (ws_size >= tbl_bytes) {
        __half2* T2 = (__half2*)d_ws;
        build_and_cat<<<NBUILD_ + NCAT_TILES_, 256, 0, stream>>>(
            W1, b1, W2, b2, x_cat, emb, gamma, beta, T2, out);
        fuse_num<<<NNUM_TILES_, 256, 0, stream>>>(T2, x_num, gamma, beta, out);
    } else {
        int nrow_blocks = (B_ * TOK_ + 3) / 4;
        fuse_exact<<<nrow_blocks, 256, 0, stream>>>(x_num, x_cat, W1, b1, W2, b2,
                                                    emb, gamma, beta, out);
    }
}